// Round 2
// baseline (250.895 us; speedup 1.0000x reference)
//
#include <hip/hip_runtime.h>
#include <cstddef>
#include <cstdint>

#define EMB 1024
#define SEQ 1500
#define NB 4
#define NH 16
#define DH 64
#define MTOT (NB*SEQ)   // 6000
#define VTS 1536        // padded V^T row stride (elements)

typedef __bf16 bf16;
typedef __bf16 bf16x4 __attribute__((ext_vector_type(4)));
typedef __bf16 bf16x8 __attribute__((ext_vector_type(8)));
typedef short  s16x4  __attribute__((ext_vector_type(4)));
typedef float  f32x4  __attribute__((ext_vector_type(4)));

#define LOG2E 1.44269504088896340736f

__device__ __forceinline__ void async16(const void* g, const void* l) {
    __builtin_amdgcn_global_load_lds(
        (const __attribute__((address_space(1))) uint32_t*)g,
        (__attribute__((address_space(3))) uint32_t*)l, 16, 0, 0);
}

// pack two fp32 to bf16x2 by truncation: one v_perm_b32
__device__ __forceinline__ uint32_t pack_bf16_trunc(float e0, float e1) {
    return __builtin_amdgcn_perm(__builtin_bit_cast(uint32_t, e1),
                                 __builtin_bit_cast(uint32_t, e0), 0x07060302u);
}

// ---------------------------------------------------------------------------
// fp32 -> bf16 conversion, flat grid over x + 4 weight matrices
// ---------------------------------------------------------------------------
struct CvtArgs {
    const float* xs; bf16* xd;
    const float* w[4]; bf16* wd[4];
};

__global__ __launch_bounds__(256) void cvt_kernel(CvtArgs a) {
    const size_t NX = (size_t)MTOT * EMB;        // 6,144,000 (mult of 4)
    const size_t NW = (size_t)EMB * EMB;         // 1<<20
    const size_t tot = NX + 4 * NW;
    for (size_t i = ((size_t)blockIdx.x * 256 + threadIdx.x) * 4; i < tot;
         i += (size_t)gridDim.x * 1024) {
        const float* s; bf16* d; size_t off;
        if (i < NX) { s = a.xs; d = a.xd; off = i; }
        else {
            size_t j = i - NX;
            int wi = (int)(j >> 20);
            off = j & (NW - 1);
            s = a.w[wi]; d = a.wd[wi];
        }
        float4 v = *(const float4*)(s + off);
        bf16x4 o = { (bf16)v.x, (bf16)v.y, (bf16)v.z, (bf16)v.w };
        *(bf16x4*)(d + off) = o;
    }
}

// ---------------------------------------------------------------------------
// QKV GEMM, 8-phase 256x256 schedule (T2+T3+T4+T5 port):
//   BM=BN=256, BK=64, 512 threads = 8 waves (2 A-dim x 4 B-dim),
//   per-wave 128x64 output, LDS 128 KiB (2 dbuf x 2 halves x [128][64] x A,B),
//   counted vmcnt(4) at phases 4/8 only, raw s_barrier (no vmcnt(0) drains),
//   3-bit XOR LDS swizzle via pre-swizzled global source, setprio around MFMA.
// proj0 Q (A=Wq swapped, (acc+b)*0.125*log2e), proj1 K (A=Wk swapped),
// proj2 V (A=X normal -> V^T store).
// ---------------------------------------------------------------------------
__global__ __launch_bounds__(512, 2) void gemm_fused(
    const bf16* __restrict__ X,
    const bf16* __restrict__ W0, const bf16* __restrict__ W1, const bf16* __restrict__ W2,
    const float* __restrict__ b_q, const float* __restrict__ b_v,
    bf16* __restrict__ Oq, bf16* __restrict__ Ok, bf16* __restrict__ Ovt,
    int M)
{
    __shared__ bf16 As[2][2][8192];   // [buf][half(128 rows)][128*64]
    __shared__ bf16 Bs[2][2][8192];

    const int tid = threadIdx.x;
    const int lane = tid & 63, w = tid >> 6;
    const int q = lane >> 4, lr = lane & 15;
    const int wa = w >> 2;            // 0..1: A-dim wave (owns A-half wa)
    const int wb = w & 3;             // 0..3: B-dim wave

    // 288 blocks: XCD-pinned m-tiles (24) x 12 (proj,n) slices
    const int id = blockIdx.x;
    const int mtile = (id & 7) + ((id >> 3) % 3) * 8;   // 0..23
    const int y = (id >> 3) / 3;                        // 0..11
    const int proj = y >> 2;
    const int n0 = (y & 3) * 256;
    const int m0 = mtile * 256;

    const bf16 *PA, *PB;
    int baseA, baseB, limA, limB;
    if (proj == 2) {
        PA = X;  baseA = m0; limA = M;
        PB = W2; baseB = n0; limB = EMB;
    } else {
        PA = (proj == 0) ? W0 : W1;
        baseA = n0; limA = EMB;
        PB = X; baseB = m0; limB = M;
    }

    // ---- staging source pointers (pre-swizzled chunk so linear LDS dest
    //      ends up XOR-swizzled: content[L] = orig[L ^ ((row&7)<<4)]) ----
    const int srow = tid >> 3;                               // 0..63
    const int sch  = ((tid & 7) ^ ((tid >> 3) & 7)) * 8;     // elems
    const bf16* gA[2][2]; const bf16* gB[2][2];
#pragma unroll
    for (int h = 0; h < 2; h++)
#pragma unroll
        for (int i = 0; i < 2; i++) {
            int ra = baseA + h * 128 + i * 64 + srow; ra = ra < limA ? ra : limA - 1;
            int rb = baseB + h * 128 + i * 64 + srow; rb = rb < limB ? rb : limB - 1;
            gA[h][i] = PA + (size_t)ra * EMB + sch;
            gB[h][i] = PB + (size_t)rb * EMB + sch;
        }

#define STAGE_AH(buf, h, kt) do { \
    async16(gA[h][0] + (kt) * 64, &As[buf][h][w * 512]); \
    async16(gA[h][1] + (kt) * 64, &As[buf][h][4096 + w * 512]); } while (0)
#define STAGE_BH(buf, h, kt) do { \
    async16(gB[h][0] + (kt) * 64, &Bs[buf][h][w * 512]); \
    async16(gB[h][1] + (kt) * 64, &Bs[buf][h][4096 + w * 512]); } while (0)

#define BAR() asm volatile("s_barrier" ::: "memory")
#define VMC4() asm volatile("s_waitcnt vmcnt(4)" ::: "memory")
#define VMC0() asm volatile("s_waitcnt vmcnt(0)" ::: "memory")

    // ---- fragment-read swizzled chunk offsets (elems) ----
    const int xoff0 = (((q * 16)      ^ ((lr & 7) << 4)) >> 1);
    const int xoff1 = (((64 + q * 16) ^ ((lr & 7) << 4)) >> 1);

    const bf16* Ab0 = &As[0][wa][0];
    const bf16* Ab1 = &As[1][wa][0];
    const bf16* Bb0 = &Bs[0][wb >> 1][(wb & 1) * 4096];
    const bf16* Bb1 = &Bs[1][wb >> 1][(wb & 1) * 4096];

    f32x4  acc[8][4] = {};
    bf16x8 a[4][2], b0[2][2], b1[2][2];

#define READ_A(P, qa) do { _Pragma("unroll") \
    for (int f = 0; f < 4; f++) { \
        a[f][0] = *(const bf16x8*)((P) + ((qa) * 4 + f) * 1024 + lr * 64 + xoff0); \
        a[f][1] = *(const bf16x8*)((P) + ((qa) * 4 + f) * 1024 + lr * 64 + xoff1); } } while (0)
#define READ_B(P, qb, br) do { _Pragma("unroll") \
    for (int g = 0; g < 2; g++) { \
        br[g][0] = *(const bf16x8*)((P) + ((qb) * 2 + g) * 1024 + lr * 64 + xoff0); \
        br[g][1] = *(const bf16x8*)((P) + ((qb) * 2 + g) * 1024 + lr * 64 + xoff1); } } while (0)
#define MFMA16(qa, qb, br) do { \
    __builtin_amdgcn_s_setprio(1); \
    _Pragma("unroll") for (int f = 0; f < 4; f++) \
    _Pragma("unroll") for (int g = 0; g < 2; g++) { \
        acc[(qa)*4+f][(qb)*2+g] = __builtin_amdgcn_mfma_f32_16x16x32_bf16( \
            a[f][0], br[g][0], acc[(qa)*4+f][(qb)*2+g], 0, 0, 0); \
        acc[(qa)*4+f][(qb)*2+g] = __builtin_amdgcn_mfma_f32_16x16x32_bf16( \
            a[f][1], br[g][1], acc[(qa)*4+f][(qb)*2+g], 0, 0, 0); } \
    __builtin_amdgcn_s_setprio(0); } while (0)

    // ---- prologue: tile0 fully + tile1.B0/B1; leave tile1.B* in flight ----
    STAGE_BH(0, 0, 0); STAGE_BH(0, 1, 0);
    STAGE_AH(0, 0, 0); STAGE_AH(0, 1, 0);
    STAGE_BH(1, 0, 1); STAGE_BH(1, 1, 1);
    VMC4();
    BAR();

    // ---- main loop: iter i computes K-tiles 2i (buf0) and 2i+1 (buf1) ----
    for (int it = 0; it < 8; ++it) {
        const int T1 = 2 * it + 1, T2 = 2 * it + 2, T3 = 2 * it + 3;
        const bool more = (it < 7);

        // ph1: quad(a0,b0); stage buf1.A0 (tile T1)
        READ_A(Ab0, 0); READ_B(Bb0, 0, b0);
        STAGE_AH(1, 0, T1);
        BAR();
        MFMA16(0, 0, b0);
        BAR();
        // ph2: quad(a0,b1); stage buf1.A1 (tile T1)
        READ_B(Bb0, 1, b1);
        STAGE_AH(1, 1, T1);
        BAR();
        MFMA16(0, 1, b1);
        BAR();
        // ph3: quad(a1,b1); stage buf0.B0 (tile T2)
        READ_A(Ab0, 1);
        if (more) STAGE_BH(0, 0, T2);
        BAR();
        MFMA16(1, 1, b1);
        BAR();
        // ph4: quad(a1,b0); stage buf0.A0 (tile T2); vmcnt -> tile T1 landed
        if (more) STAGE_AH(0, 0, T2);
        BAR();
        MFMA16(1, 0, b0);
        if (more) { VMC4(); } else { VMC0(); }
        BAR();
        // ph5: tile T1 quad(a0,b0); stage buf0.B1 (tile T2)
        READ_A(Ab1, 0); READ_B(Bb1, 0, b0);
        if (more) STAGE_BH(0, 1, T2);
        BAR();
        MFMA16(0, 0, b0);
        BAR();
        // ph6: quad(a0,b1); stage buf0.A1 (tile T2)
        READ_B(Bb1, 1, b1);
        if (more) STAGE_AH(0, 1, T2);
        BAR();
        MFMA16(0, 1, b1);
        BAR();
        // ph7: quad(a1,b1); stage buf1.B0 (tile T3)
        READ_A(Ab1, 1);
        if (more) STAGE_BH(1, 0, T3);
        BAR();
        MFMA16(1, 1, b1);
        BAR();
        // ph8: quad(a1,b0); stage buf1.B1 (tile T3); vmcnt -> tile T2 landed
        if (more) STAGE_BH(1, 1, T3);
        BAR();
        MFMA16(1, 0, b0);
        if (more) VMC4();
        BAR();
    }

#undef STAGE_AH
#undef STAGE_BH
#undef BAR
#undef VMC4
#undef VMC0
#undef READ_A
#undef READ_B
#undef MFMA16

    // ---- epilogue ----
    // D-layout: A-side index = wa*128 + am*16 + q*4 + r, B-side = wb*64 + bn*16 + lr
    if (proj <= 1) {
        const float scale = (proj == 0) ? 0.125f * LOG2E : 1.0f;
        const float* bias = (proj == 0) ? b_q : nullptr;
        bf16* O = (proj == 0) ? Oq : Ok;
#pragma unroll
        for (int bn = 0; bn < 4; bn++) {
            const int m = m0 + wb * 64 + bn * 16 + lr;
            if (m >= M) continue;
            const int b_ = m / SEQ, s_ = m % SEQ;
#pragma unroll
            for (int am = 0; am < 8; am++) {
                const int nb = n0 + wa * 128 + am * 16 + q * 4;
                const int h = nb >> 6, d = nb & 63;
                float4 b4 = bias ? *(const float4*)(bias + nb)
                                 : make_float4(0.f, 0.f, 0.f, 0.f);
                bf16x4 o;
                o[0] = (bf16)((acc[am][bn][0] + b4.x) * scale);
                o[1] = (bf16)((acc[am][bn][1] + b4.y) * scale);
                o[2] = (bf16)((acc[am][bn][2] + b4.z) * scale);
                o[3] = (bf16)((acc[am][bn][3] + b4.w) * scale);
                *(bf16x4*)(O + (((size_t)b_ * NH + h) * SEQ + s_) * DH + d) = o;
            }
        }
    } else {
#pragma unroll
        for (int am = 0; am < 8; am++) {
            const int mb = m0 + wa * 128 + am * 16 + q * 4;
            if (mb >= M) continue;
            const int b_ = mb / SEQ, s_ = mb % SEQ;
#pragma unroll
            for (int bn = 0; bn < 4; bn++) {
                const int nb = n0 + wb * 64 + bn * 16 + lr;
                const int h = nb >> 6, d = nb & 63;
                const float bv = b_v[nb];
                bf16x4 o;
                o[0] = (bf16)(acc[am][bn][0] + bv);
                o[1] = (bf16)(acc[am][bn][1] + bv);
                o[2] = (bf16)(acc[am][bn][2] + bv);
                o[3] = (bf16)(acc[am][bn][3] + bv);
                *(bf16x4*)(Ovt + ((size_t)(b_ * NH + h) * DH + d) * VTS + s_) = o;
            }
        }
    }
}

// ---------------------------------------------------------------------------
// Out-projection GEMM (r8): 128m x 64n tile, 4-wave blocks, grid 768.
// A=Wo (64 n-rows), B=ctx (128 m-rows), D=C^T -> fp32 b128 stores.
// dbuf + XOR swizzle + XCD-pinned m-tiles.
// ---------------------------------------------------------------------------
__global__ __launch_bounds__(256) void gemm_out(
    const bf16* __restrict__ X, const bf16* __restrict__ Wo,
    const float* __restrict__ b_o, float* __restrict__ Of, int M)
{
    __shared__ bf16 As[2][64 * 32];    // Wo n-rows
    __shared__ bf16 Bs[2][128 * 32];   // X m-rows
    const int tid = threadIdx.x;
    const int lane = tid & 63, w = tid >> 6;
    const int q = lane >> 4, lr = lane & 15;
    const int wc = w & 1, wr = w >> 1;   // wc: m-half (64), wr: n-half (32)

    const int id = blockIdx.x;           // 768 = 8 xcd * 96
    const int xcd = id & 7;
    const int h = id >> 3;               // 0..95
    const int mtile = (h % 6) * 8 + xcd; // 0..47
    const int ntile = h / 6;             // 0..15
    const int m0 = mtile * 128, n0 = ntile * 64;

    const int cs = ((tid & 3) ^ ((tid >> 3) & 3)) * 8;   // swizzled source chunk
    const bf16* pA = Wo + (size_t)(n0 + (tid >> 2)) * EMB + cs;
    const int srow = w * 32 + (lane >> 2);
    const bf16* pB[2];
#pragma unroll
    for (int i = 0; i < 2; i++) {
        int rb = m0 + srow + i * 16; rb = rb < M ? rb : M - 1;
        pB[i] = X + (size_t)rb * EMB + cs;
    }

    async16(pA, As[0] + w * 512);
#pragma unroll
    for (int i = 0; i < 2; i++)
        async16(pB[i], Bs[0] + (w * 2 + i) * 512);

    f32x4 acc[2][4] = {};
    const int qsw = (q ^ ((lr >> 1) & 3)) * 8;
    const int arow = (wr * 32 + lr) * 32;
    const int brow = (wc * 64 + lr) * 32;

    for (int k0 = 0; k0 < EMB; k0 += 32) {
        const int cur = (k0 >> 5) & 1;
        __syncthreads();
        const int nxt = k0 + 32;
        if (nxt < EMB) {
            async16(pA + nxt, As[cur ^ 1] + w * 512);
#pragma unroll
            for (int i = 0; i < 2; i++)
                async16(pB[i] + nxt, Bs[cur ^ 1] + (w * 2 + i) * 512);
        }
        bf16x8 af[2], bfr[4];
#pragma unroll
        for (int t = 0; t < 2; t++)
            af[t] = *(const bf16x8*)(As[cur] + arow + t * 512 + qsw);
#pragma unroll
        for (int t = 0; t < 4; t++)
            bfr[t] = *(const bf16x8*)(Bs[cur] + brow + t * 512 + qsw);
#pragma unroll
        for (int ti = 0; ti < 2; ti++)
#pragma unroll
            for (int tj = 0; tj < 4; tj++)
                acc[ti][tj] = __builtin_amdgcn_mfma_f32_16x16x32_bf16(
                    af[ti], bfr[tj], acc[ti][tj], 0, 0, 0);
    }

    // D = C^T: n = n0 + wr*32 + ti*16 + q*4 + r, m = m0 + wc*64 + tj*16 + lr
#pragma unroll
    for (int tj = 0; tj < 4; tj++) {
        const int m = m0 + wc * 64 + tj * 16 + lr;
        if (m >= M) continue;
#pragma unroll
        for (int ti = 0; ti < 2; ti++) {
            const int nb = n0 + wr * 32 + ti * 16 + q * 4;
            const float4 b4 = *(const float4*)(b_o + nb);
            float4 o;
            o.x = acc[ti][tj][0] + b4.x;
            o.y = acc[ti][tj][1] + b4.y;
            o.z = acc[ti][tj][2] + b4.z;
            o.w = acc[ti][tj][3] + b4.w;
            *(float4*)(Of + (size_t)m * EMB + nb) = o;
        }
    }
}

// ---------------------------------------------------------------------------
// bf16 MFMA flash attention, 192 Q-rows/block (THREE 16-row groups per
// wave). K-frags and V-frags are loaded once per iter and shared across all
// 3 groups. S^T = K.Q^T trick, V pre-transposed, async16 dbuf staging with
// XOR swizzle, 1 barrier/iter, P packed by v_perm truncation, lsum on the
// MFMA pipe, raw exp2.
// ---------------------------------------------------------------------------
#define QG 3
__global__ __launch_bounds__(256) void attn_mfma(
    const bf16* __restrict__ Qb, const bf16* __restrict__ Kb,
    const bf16* __restrict__ Vt, bf16* __restrict__ ctx)
{
    __shared__ bf16 Ks[2][64 * 64];
    __shared__ bf16 Vs[2][64 * 64];   // V^T tile: row d, col key
    const int tid = threadIdx.x;
    const int lane = tid & 63, w = tid >> 6;
    const int q = lane >> 4, lr = lane & 15;
    const int bh = blockIdx.x, b_ = bh >> 4, h_ = bh & 15;
    const int q0 = blockIdx.y * (QG * 64);
    const size_t base = (size_t)bh * SEQ * DH;
    const size_t vbase = (size_t)bh * DH * VTS;

    int qrow[QG];
    bf16x8 qf[QG][2];
#pragma unroll
    for (int g = 0; g < QG; g++) {
        qrow[g] = q0 + g * 64 + w * 16 + lr;
        const int qrc = qrow[g] < SEQ ? qrow[g] : (SEQ - 1);
        qf[g][0] = *(const bf16x8*)(Qb + base + (size_t)qrc * DH + q * 8);
        qf[g][1] = *(const bf16x8*)(Qb + base + (size_t)qrc * DH + 32 + q * 8);
    }

    f32x4 oacc[QG][4] = {};
    f32x4 lacc[QG] = {};
    const s16x4 ones = { (short)0x3F80, (short)0x3F80, (short)0x3F80, (short)0x3F80 };

    const int srow = tid >> 3;                       // 0..31 staging row
    const int sch8 = ((tid & 7) ^ (srow & 7)) * 8;   // swizzled source chunk (elems)
    const int kswz = lr & 7;                          // frag un-swizzle key

    const int NT = (SEQ + 63) / 64;    // 24

    {
        int r0 = srow, r1 = srow + 32;
        async16(Kb + base + (size_t)r0 * DH + sch8, Ks[0] + tid * 8);
        async16(Kb + base + (size_t)r1 * DH + sch8, Ks[0] + tid * 8 + 2048);
        async16(Vt + vbase + (size_t)srow * VTS + sch8,        Vs[0] + tid * 8);
        async16(Vt + vbase + (size_t)(srow + 32) * VTS + sch8, Vs[0] + tid * 8 + 2048);
    }

    for (int kt = 0; kt < NT; kt++) {
        const int k0 = kt * 64;
        const int cur = kt & 1;
        __syncthreads();   // buf[cur] landed (vmcnt drained); buf[cur^1] consumed

        if (kt + 1 < NT) {
            const int kn = k0 + 64;
            int r0 = kn + srow;      if (r0 >= SEQ) r0 = SEQ - 1;
            int r1 = kn + srow + 32; if (r1 >= SEQ) r1 = SEQ - 1;
            async16(Kb + base + (size_t)r0 * DH + sch8, Ks[cur ^ 1] + tid * 8);
            async16(Kb + base + (size_t)r1 * DH + sch8, Ks[cur ^ 1] + tid * 8 + 2048);
            async16(Vt + vbase + (size_t)srow * VTS + kn + sch8,
                    Vs[cur ^ 1] + tid * 8);
            async16(Vt + vbase + (size_t)(srow + 32) * VTS + kn + sch8,
                    Vs[cur ^ 1] + tid * 8 + 2048);
        }

        const bf16* Kc = Ks[cur];
        const bf16* Vc = Vs[cur];

        // K fragments, shared by all Q-groups
        bf16x8 kf[2][4];
#pragma unroll
        for (int s = 0; s < 2; s++)
#pragma unroll
            for (int mt = 0; mt < 4; mt++)
                kf[s][mt] = *(const bf16x8*)(Kc + (mt * 16 + lr) * 64 +
                                             ((4 * s + q) ^ kswz) * 8);

        s16x4 pf[QG][4];
#pragma unroll
        for (int g = 0; g < QG; g++) {
            f32x4 st[4] = {};
#pragma unroll
            for (int s = 0; s < 2; s++)
#pragma unroll
                for (int mt = 0; mt < 4; mt++)
                    st[mt] = __builtin_amdgcn_mfma_f32_16x16x32_bf16(
                        kf[s][mt], qf[g][s], st[mt], 0, 0, 0);

            if (k0 + 64 > SEQ) {
#pragma unroll
                for (int mt = 0; mt < 4; mt++)
#pragma unroll
                    for (int r = 0; r < 4; r++)
                        if (k0 + mt * 16 + q * 4 + r >= SEQ) st[mt][r] = -16384.0f;
            }

#pragma unroll
            for (int mt = 0; mt < 4; mt++) {
                float e0 = __builtin_amdgcn_exp2f(st[mt][0]);
                float e1 = __builtin_amdgcn_exp2f(st[mt][1]);
                float e2 = __builtin_amdgcn_exp2f(st[mt][2]);
                float e3 = __builtin_amdgcn_exp2f(st[mt][3]);
                uint32_t lo = pack_bf16_trunc(e0, e1);
                uint32_t hi = pack_bf16_trunc(e2, e3);
                uint2 pk = { lo, hi };
                pf[g][mt] = __builtin_bit_cast(s16x4, pk);
            }
#pragma unroll
            for (int c = 0; c < 4; c++)
                lacc[g] = __builtin_amdgcn_mfma_f32_16x16x16bf16_1k(
                    ones, pf[g][c], lacc[g], 0, 0, 0);
        }

        // O^T += V^T . P^T, V fragments shared by all groups
#pragma unroll
        for (int c = 0; c < 4; c++) {
#pragma unroll
            for (int dt = 0; dt < 4; dt++) {
                const s16x4 vf = __builtin_bit_cast(s16x4,
                    *(const bf16x4*)(Vc + (dt * 16 + lr) * 64 +
                                     ((2 * c + (q >> 1)) ^ kswz) * 8 + (q & 1) * 4));
#pragma unroll
                for (int g = 0; g < QG; g++)
                    oacc[g][dt] = __builtin_amdgcn_mfma_f32_16x16x16bf16_1k(
                        vf, pf[g][c], oacc[g][dt], 0, 0, 0);
            }
        }
    }

    // epilogue: lane lr's col of lacc == its Q-row sum; no shuffles needed
#pragma unroll
    for (int g = 0; g < QG; g++) {
        const float inv = 1.0f / lacc[g][0];
        if (qrow[g] < SEQ) {
            const size_t rowoff = ((size_t)b_ * SEQ + qrow[g]) * EMB + h_ * DH;
#pragma unroll
            for (int dt = 0; dt < 4; dt++) {
                bf16x4 o;
#pragma unroll
                for (int r = 0; r < 4; r++) o[r] = (bf16)(oacc[g][dt][r] * inv);
                *(bf16x4*)(ctx + rowoff + dt * 16 + q * 4) = o;
            }
        }
    }
}

extern "C" void kernel_launch(void* const* d_in, const int* in_sizes, int n_in,
                              void* d_out, int out_size, void* d_ws, size_t ws_size,
                              hipStream_t stream) {
    const float* x     = (const float*)d_in[0];
    const float* q_w   = (const float*)d_in[1];
    const float* q_b   = (const float*)d_in[2];
    const float* k_w   = (const float*)d_in[3];
    const float* v_w   = (const float*)d_in[4];
    const float* v_b   = (const float*)d_in[5];
    const float* out_w = (const float*)d_in[6];
    const float* out_b = (const float*)d_in[7];
    float* out = (float*)d_out;

    const size_t nbuf = (size_t)MTOT * EMB;         // 6,144,000
    const size_t nvt  = (size_t)NB * NH * DH * VTS; // 6,291,456
    const size_t nw   = (size_t)EMB * EMB;          // 1,048,576
    bf16* xb  = (bf16*)d_ws;        // reused as ctx after QKV
    bf16* qws = xb  + nbuf;
    bf16* kws = qws + nbuf;
    bf16* vtw = kws + nbuf;
    bf16* wqb = vtw + nvt;
    bf16* wkb = wqb + nw;
    bf16* wvb = wkb + nw;
    bf16* wob = wvb + nw;
    bf16* ctx = xb;                 // alias: x dead after QKV GEMM

    CvtArgs ca;
    ca.xs = x;      ca.xd = xb;
    ca.w[0] = q_w;  ca.wd[0] = wqb;
    ca.w[1] = k_w;  ca.wd[1] = wkb;
    ca.w[2] = v_w;  ca.wd[2] = wvb;
    ca.w[3] = out_w; ca.wd[3] = wob;
    cvt_kernel<<<dim3(2560), 256, 0, stream>>>(ca);

    // fused QKV projections: 24 m-tiles x 12 (proj,n) slices, 8-phase 256^2
    gemm_fused<<<dim3(288), 512, 0, stream>>>(
        xb, wqb, wkb, wvb, q_b, v_b, qws, kws, vtw, MTOT);

    // attention -> ctx [B,S,E] bf16; 192 Q-rows per block
    attn_mfma<<<dim3(NB * NH, (SEQ + QG * 64 - 1) / (QG * 64)), 256, 0, stream>>>(
        qws, kws, vtw, ctx);

    // output projection -> d_out (fp32): 128x64 tiles, 768 blocks (3/CU)
    gemm_out<<<dim3(768), 256, 0, stream>>>(ctx, wob, out_b, out, MTOT);
}